// Round 2
// baseline (1053.043 us; speedup 1.0000x reference)
//
#include <hip/hip_runtime.h>
#include <hip/hip_bf16.h>
#include <cstdint>

#define RINGN 256
#define DD    128
#define SDN   42
#define G3N   126
#define INN   64
#define BN    512
#define TN    512
#define NCN   1000
#define HS    44      // padded h row stride (floats), 176B = 11 x float4

__device__ __forceinline__ float sigm(float x)    { return 1.0f / (1.0f + __expf(-x)); }
__device__ __forceinline__ float tanhfast(float x){ float e = __expf(2.0f * x); return 1.0f - 2.0f / (e + 1.0f); }
__device__ __forceinline__ float wrap256(float x) { return x - 256.0f * floorf(x * 0.00390625f); }

// Gaussian soft window around fractional ring pointer (5 taps, tau=8)
__device__ __forceinline__ void taps(float p, int* pos, float* w) {
  float base = floorf(p);
  float frac = p - base;
  int ib = (int)base;
  float e[5];
  float s = 0.0f;
#pragma unroll
  for (int k = 0; k < 5; k++) {
    float d = (float)(k - 2) - frac;
    e[k] = __expf(-(d * d) * 0.125f);
    s += e[k];
    pos[k] = (ib + k - 2) & 255;
  }
  float inv = 1.0f / s;
#pragma unroll
  for (int k = 0; k < 5; k++) w[k] = e[k] * inv;
}

// ---------------- prep: Wc = W_ih @ W_proj  [126][64], bc = b_ih + W_ih @ b_proj ----------------
__global__ void prep_kernel(const float* __restrict__ w_ih, const float* __restrict__ w_proj,
                            const float* __restrict__ b_proj, const float* __restrict__ b_ih,
                            float* __restrict__ Wc, float* __restrict__ bc) {
  int idx = blockIdx.x * 256 + threadIdx.x;
  if (idx < G3N * INN) {
    int j = idx / INN, i = idx % INN;
    float a = 0.0f;
    for (int k = 0; k < SDN; k++) a += w_ih[j * SDN + k] * w_proj[k * INN + i];
    Wc[idx] = a;
  }
  if (idx < G3N) {
    float a = b_ih[idx];
    for (int k = 0; k < SDN; k++) a += w_ih[idx * SDN + k] * b_proj[k];
    bc[idx] = a;
  }
}

// ---------------- gx GEMM: gx[B*T][126] = X[B*T][64] @ Wc.T + bc ----------------
__global__ __launch_bounds__(256)
void gx_gemm(const float* __restrict__ x, const float* __restrict__ Wc,
             const float* __restrict__ bc, float* __restrict__ gx) {
  const size_t row = (size_t)blockIdx.x * 256 + threadIdx.x;  // 262144 rows exactly
  float xr[INN];
#pragma unroll
  for (int i4 = 0; i4 < INN / 4; i4++) {
    float4 v = *reinterpret_cast<const float4*>(&x[row * INN + i4 * 4]);
    xr[i4 * 4 + 0] = v.x; xr[i4 * 4 + 1] = v.y; xr[i4 * 4 + 2] = v.z; xr[i4 * 4 + 3] = v.w;
  }
  for (int c = 0; c < G3N; c++) {
    float acc = bc[c];
    const float* wrow = &Wc[c * INN];
#pragma unroll
    for (int i4 = 0; i4 < INN / 4; i4++) {
      float4 wv = *reinterpret_cast<const float4*>(&wrow[i4 * 4]);
      acc += wv.x * xr[i4 * 4 + 0] + wv.y * xr[i4 * 4 + 1] + wv.z * xr[i4 * 4 + 2] + wv.w * xr[i4 * 4 + 3];
    }
    gx[row * G3N + c] = acc;
  }
}

// ---------------- recurrence: one wave per batch element, wave-synchronous (NO barriers) ----------------
__global__ __launch_bounds__(64, 1)
void rec_kernel(const float* __restrict__ gx,       // [B][T][126]
                const float* __restrict__ w_hh,     // [126][42]
                const float* __restrict__ b_hh,     // [126]
                const float* __restrict__ w_bridge, // [128][42]
                const float* __restrict__ b_bridge, // [128]
                const float* __restrict__ w_jump,   // [128]
                const float* __restrict__ b_jump,   // [1]
                const float* __restrict__ w_gate,   // [128]
                const float* __restrict__ b_gate,   // [1]
                const float* __restrict__ theta,    // [1]
                float* __restrict__ hbuf,           // [B][T][HS]
                float* __restrict__ ptrbuf) {       // [B][T]
  const int b = blockIdx.x;
  const int lane = threadIdx.x;
  const int r1 = lane + 64;

  __shared__ float Jld[RINGN];
  __shared__ float Gld[RINGN];
  __shared__ __align__(16) float h_buf[HS];
  __shared__ float gh_buf[128];

  for (int i = lane; i < RINGN; i += 64) { Jld[i] = 0.0f; Gld[i] = 0.0f; }

  // per-lane register-resident weight rows (float2 for packed FMA)
  const float2* whh2 = (const float2*)w_hh;
  const float2* wb2  = (const float2*)w_bridge;
  float2 Whh0[21], Whh1[21], Wb0[21], Wb1[21];
#pragma unroll
  for (int k = 0; k < 21; k++) {
    Whh0[k] = whh2[lane * 21 + k];
    Whh1[k] = (r1 < G3N) ? whh2[r1 * 21 + k] : make_float2(0.f, 0.f);
    Wb0[k]  = wb2[lane * 21 + k];
    Wb1[k]  = wb2[r1 * 21 + k];
  }
  float bh0 = b_hh[lane];
  float bh1 = (r1 < G3N) ? b_hh[r1] : 0.0f;
  float bb0 = b_bridge[lane], bb1 = b_bridge[r1];
  float wj0 = w_jump[lane], wj1 = w_jump[r1];
  float wg0 = w_gate[lane], wg1 = w_gate[r1];
  float bj = b_jump[0], bg = b_gate[0];

  float2 hv2[22];
#pragma unroll
  for (int k = 0; k < 22; k++) hv2[k] = make_float2(0.f, 0.f);
  float hprev = 0.0f;

  float ptr = wrap256(theta[0]);

  const float* gxb = gx + (size_t)b * TN * G3N;
  float* hb = hbuf + (size_t)b * TN * HS;
  float* pb = ptrbuf + (size_t)b * TN;

  float pgx0 = 0.0f, pgx1 = 0.0f, pgx2 = 0.0f;
  if (lane < SDN) {
    pgx0 = gxb[lane];
    pgx1 = gxb[SDN + lane];
    pgx2 = gxb[2 * SDN + lane];
  }

  __builtin_amdgcn_wave_barrier();

  for (int t = 0; t < TN; t++) {
    // ---- pointer chain (replicated scalar math; reads J/G written at end of prev iter) ----
    int pos[5]; float w[5];
    taps(ptr, pos, w);
    float Jv = 0.0f, Gv = 0.0f;
#pragma unroll
    for (int k = 0; k < 5; k++) { Jv += w[k] * Jld[pos[k]]; Gv += w[k] * Gld[pos[k]]; }
    float jump = 256.0f * sigm(Jv + bj);
    float gate = sigm(Gv + bg);
    float delta = wrap256(jump - ptr + 128.0f) - 128.0f;
    float ptr2 = wrap256(ptr + gate * delta);
    int pos2[5]; float w2[5];
    taps(ptr2, pos2, w2);
    if (lane == 0) pb[t] = ptr2;

    // ---- gh = W_hh @ h + b_hh (rows lane, lane+64), 4 partial chains ----
    float2 s0a = make_float2(0.f, 0.f), s0b = make_float2(0.f, 0.f);
    float2 s1a = make_float2(0.f, 0.f), s1b = make_float2(0.f, 0.f);
#pragma unroll
    for (int k = 0; k < 21; k++) {
      float2 w0 = Whh0[k], w1 = Whh1[k], h2 = hv2[k];
      if (k & 1) { s0b.x += w0.x * h2.x; s0b.y += w0.y * h2.y; s1b.x += w1.x * h2.x; s1b.y += w1.y * h2.y; }
      else       { s0a.x += w0.x * h2.x; s0a.y += w0.y * h2.y; s1a.x += w1.x * h2.x; s1a.y += w1.y * h2.y; }
    }
    float gh0 = bh0 + ((s0a.x + s0b.x) + (s0a.y + s0b.y));
    float gh1 = bh1 + ((s1a.x + s1b.x) + (s1a.y + s1b.y));
    gh_buf[lane] = gh0;
    gh_buf[64 + lane] = gh1;
    __builtin_amdgcn_wave_barrier();

    // ---- gates (lanes 0..41), h' write, h store to global ----
    if (lane < SDN) {
      float ghr = gh_buf[lane];
      float ghz = gh_buf[SDN + lane];
      float ghn = gh_buf[2 * SDN + lane];
      float rg = sigm(pgx0 + ghr);
      float zg = sigm(pgx1 + ghz);
      float ng = tanhfast(pgx2 + rg * ghn);
      float hn = (1.0f - zg) * ng + zg * hprev;
      hprev = hn;
      h_buf[lane] = hn;
      hb[(size_t)t * HS + lane] = hn;   // fire-and-forget coalesced store
    }
    __builtin_amdgcn_wave_barrier();

    // ---- broadcast h' to all lanes (float4 LDS reads) ----
#pragma unroll
    for (int k4 = 0; k4 < 11; k4++) {
      float4 v = *reinterpret_cast<const float4*>(&h_buf[k4 * 4]);
      hv2[k4 * 2 + 0] = make_float2(v.x, v.y);
      hv2[k4 * 2 + 1] = make_float2(v.z, v.w);
    }

    // ---- prefetch gx for t+1 (consumed next iter: latency hidden) ----
    if (t + 1 < TN && lane < SDN) {
      const float* g2 = gxb + (size_t)(t + 1) * G3N;
      pgx0 = g2[lane]; pgx1 = g2[SDN + lane]; pgx2 = g2[2 * SDN + lane];
    }

    // ---- u = tanh(W_bridge @ h' + b) for dims lane, lane+64 ----
    float2 t0a = make_float2(0.f, 0.f), t0b = make_float2(0.f, 0.f);
    float2 t1a = make_float2(0.f, 0.f), t1b = make_float2(0.f, 0.f);
#pragma unroll
    for (int k = 0; k < 21; k++) {
      float2 w0 = Wb0[k], w1 = Wb1[k], h2 = hv2[k];
      if (k & 1) { t0b.x += w0.x * h2.x; t0b.y += w0.y * h2.y; t1b.x += w1.x * h2.x; t1b.y += w1.y * h2.y; }
      else       { t0a.x += w0.x * h2.x; t0a.y += w0.y * h2.y; t1a.x += w1.x * h2.x; t1a.y += w1.y * h2.y; }
    }
    float u0 = tanhfast(bb0 + ((t0a.x + t0b.x) + (t0a.y + t0b.y)));
    float u1 = tanhfast(bb1 + ((t1a.x + t1b.x) + (t1a.y + t1b.y)));

    // ---- pj = u . w_jump, pg = u . w_gate (64-lane butterfly) ----
    float pj = u0 * wj0 + u1 * wj1;
    float pg = u0 * wg0 + u1 * wg1;
#pragma unroll
    for (int m = 32; m >= 1; m >>= 1) {
      pj += __shfl_xor(pj, m, 64);
      pg += __shfl_xor(pg, m, 64);
    }

    // ---- J/G incremental update (lanes 0..4, static-index selection) ----
    int myp2 = pos2[0]; float myw2 = w2[0];
#pragma unroll
    for (int k = 1; k < 5; k++) {
      if (lane == k) { myp2 = pos2[k]; myw2 = w2[k]; }
    }
    if (lane < 5) {
      Jld[myp2] += myw2 * pj;
      Gld[myp2] += myw2 * pg;
    }
    __builtin_amdgcn_wave_barrier();

    ptr = ptr2;
  }
}

// ---------------- r reconstruction: r[b] = sum_t c(t) * tanh(Wb h(t) + bb) ----------------
__global__ __launch_bounds__(64)
void rfinal_kernel(const float* __restrict__ hbuf, const float* __restrict__ ptrbuf,
                   const float* __restrict__ w_bridge, const float* __restrict__ b_bridge,
                   float* __restrict__ rbuf) {
  const int b = blockIdx.x;
  const int chunk = blockIdx.y;     // 4 chunks of 128 steps
  const int lane = threadIdx.x;
  const int t0 = chunk * 128;
  const int r1 = lane + 64;

  __shared__ float c_lds[128];

  const float* pb = ptrbuf + (size_t)b * TN;
  float ptrf = pb[TN - 1];
  int posf[5]; float wf[5];
  taps(ptrf, posf, wf);

#pragma unroll
  for (int rr = 0; rr < 2; rr++) {
    int tt = rr * 64 + lane;
    int p2[5]; float w2[5];
    taps(pb[t0 + tt], p2, w2);
    float c = 0.0f;
#pragma unroll
    for (int k = 0; k < 5; k++)
#pragma unroll
      for (int k2 = 0; k2 < 5; k2++)
        c += (posf[k] == p2[k2]) ? wf[k] * w2[k2] : 0.0f;
    c_lds[tt] = c;
  }
  __builtin_amdgcn_wave_barrier();

  // Wb rows for d = lane, lane+64
  const float2* wb2 = (const float2*)w_bridge;
  float2 Wb0[21], Wb1[21];
#pragma unroll
  for (int k = 0; k < 21; k++) { Wb0[k] = wb2[lane * 21 + k]; Wb1[k] = wb2[r1 * 21 + k]; }
  float bb0 = b_bridge[lane], bb1 = b_bridge[r1];

  float racc0 = 0.0f, racc1 = 0.0f;
  for (int tt = 0; tt < 128; tt++) {
    float ct = c_lds[tt];              // uniform across wave -> uniform branch
    if (ct != 0.0f) {
      const float4* hp = (const float4*)(hbuf + ((size_t)b * TN + t0 + tt) * HS);
      float hx[44];
#pragma unroll
      for (int i = 0; i < 11; i++) {
        float4 v = hp[i];
        hx[4 * i] = v.x; hx[4 * i + 1] = v.y; hx[4 * i + 2] = v.z; hx[4 * i + 3] = v.w;
      }
      float a0 = bb0, a1 = bb1, b0 = 0.f, b1 = 0.f;
#pragma unroll
      for (int k = 0; k < 42; k += 2) {
        float2 w0 = Wb0[k / 2], w1 = Wb1[k / 2];
        a0 += w0.x * hx[k]; b0 += w0.y * hx[k + 1];
        a1 += w1.x * hx[k]; b1 += w1.y * hx[k + 1];
      }
      racc0 += ct * tanhfast(a0 + b0);
      racc1 += ct * tanhfast(a1 + b1);
    }
  }
  atomicAdd(&rbuf[b * DD + lane], racc0);
  atomicAdd(&rbuf[b * DD + 64 + lane], racc1);
}

// ---------------- classifier: out = r @ w_cls.T + b_cls ----------------
__global__ __launch_bounds__(256)
void cls_kernel(const float* __restrict__ rbuf, const float* __restrict__ w_cls,
                const float* __restrict__ b_cls, float* __restrict__ out) {
  const int b = blockIdx.x;
  const int tid = threadIdx.x;
  __shared__ __align__(16) float r[DD];
  if (tid < DD) r[tid] = rbuf[b * DD + tid];
  __syncthreads();

  for (int c = tid; c < NCN; c += 256) {
    float acc = b_cls[c];
    const float* wrow = &w_cls[(size_t)c * DD];
#pragma unroll
    for (int d4 = 0; d4 < DD / 4; d4++) {
      float4 wv = *reinterpret_cast<const float4*>(&wrow[d4 * 4]);
      float4 rv = *reinterpret_cast<const float4*>(&r[d4 * 4]);
      acc += wv.x * rv.x + wv.y * rv.y + wv.z * rv.z + wv.w * rv.w;
    }
    out[(size_t)b * NCN + c] = acc;
  }
}

extern "C" void kernel_launch(void* const* d_in, const int* in_sizes, int n_in,
                              void* d_out, int out_size, void* d_ws, size_t ws_size,
                              hipStream_t stream) {
  const float* x        = (const float*)d_in[0];
  const float* theta    = (const float*)d_in[1];
  const float* w_proj   = (const float*)d_in[2];
  const float* b_proj   = (const float*)d_in[3];
  const float* w_ih     = (const float*)d_in[4];
  const float* w_hh     = (const float*)d_in[5];
  const float* b_ih     = (const float*)d_in[6];
  const float* b_hh     = (const float*)d_in[7];
  const float* w_bridge = (const float*)d_in[8];
  const float* b_bridge = (const float*)d_in[9];
  const float* w_jump   = (const float*)d_in[10];
  const float* b_jump   = (const float*)d_in[11];
  const float* w_gate   = (const float*)d_in[12];
  const float* b_gate   = (const float*)d_in[13];
  const float* w_cls    = (const float*)d_in[14];
  const float* b_cls    = (const float*)d_in[15];
  float* out = (float*)d_out;

  char* ws = (char*)d_ws;
  size_t off = 0;
  float* gx     = (float*)(ws + off); off += (size_t)BN * TN * G3N * 4;  // 132 MB
  float* hbuf   = (float*)(ws + off); off += (size_t)BN * TN * HS * 4;   // 46 MB
  float* ptrbuf = (float*)(ws + off); off += (size_t)BN * TN * 4;        // 1 MB
  float* rbuf   = (float*)(ws + off); off += (size_t)BN * DD * 4;        // 256 KB
  float* Wc     = (float*)(ws + off); off += (((size_t)G3N * INN * 4 + 255) & ~(size_t)255);
  float* bc     = (float*)(ws + off); off += 512;

  hipMemsetAsync(rbuf, 0, (size_t)BN * DD * 4, stream);
  prep_kernel<<<32, 256, 0, stream>>>(w_ih, w_proj, b_proj, b_ih, Wc, bc);
  gx_gemm<<<(BN * TN) / 256, 256, 0, stream>>>(x, Wc, bc, gx);
  rec_kernel<<<BN, 64, 0, stream>>>(gx, w_hh, b_hh, w_bridge, b_bridge,
                                    w_jump, b_jump, w_gate, b_gate, theta, hbuf, ptrbuf);
  dim3 gfin(BN, 4);
  rfinal_kernel<<<gfin, 64, 0, stream>>>(hbuf, ptrbuf, w_bridge, b_bridge, rbuf);
  cls_kernel<<<BN, 256, 0, stream>>>(rbuf, w_cls, b_cls, out);
}

// Round 3
// 732.881 us; speedup vs baseline: 1.4369x; 1.4369x over previous
//
#include <hip/hip_runtime.h>
#include <hip/hip_bf16.h>
#include <cstdint>

#define RINGN 256
#define DD    128
#define SDN   42
#define G3N   126
#define INN   64
#define BN    512
#define TN    512
#define NCN   1000
#define HS    44          // padded h row stride (floats)
#define BT    (BN * TN)   // 262144 rows

typedef float v2f __attribute__((ext_vector_type(2)));

__device__ __forceinline__ float sigm(float x)    { return 1.0f / (1.0f + __expf(-x)); }
__device__ __forceinline__ float tanhfast(float x){ float e = __expf(2.0f * x); return 1.0f - 2.0f / (e + 1.0f); }
__device__ __forceinline__ float wrap256(float x) { return x - 256.0f * floorf(x * 0.00390625f); }

// normalized taps (for non-critical kernels)
__device__ __forceinline__ void taps_norm(float p, int* pos, float* w) {
  float base = floorf(p);
  float frac = p - base;
  int ib = (int)base;
  float e[5];
  float s = 0.0f;
#pragma unroll
  for (int k = 0; k < 5; k++) {
    float d = (float)(k - 2) - frac;
    e[k] = __expf(-(d * d) * 0.125f);
    s += e[k];
    pos[k] = (ib + k - 2) & 255;
  }
  float inv = 1.0f / s;
#pragma unroll
  for (int k = 0; k < 5; k++) w[k] = e[k] * inv;
}

// DPP full-wave sum, result broadcast via readlane(63)
template<int C>
__device__ __forceinline__ float dpp_add_step(float x) {
  int t = __builtin_amdgcn_update_dpp(0, __float_as_int(x), C, 0xf, 0xf, true);
  return x + __int_as_float(t);
}
__device__ __forceinline__ float wave_sum64(float x) {
  x = dpp_add_step<0x111>(x);  // row_shr:1
  x = dpp_add_step<0x112>(x);  // row_shr:2
  x = dpp_add_step<0x114>(x);  // row_shr:4
  x = dpp_add_step<0x118>(x);  // row_shr:8
  x = dpp_add_step<0x142>(x);  // row_bcast:15
  x = dpp_add_step<0x143>(x);  // row_bcast:31
  return __int_as_float(__builtin_amdgcn_readlane(__float_as_int(x), 63));
}

// ---------------- prep: Wc = W_ih @ W_proj  [126][64], bc = b_ih + W_ih @ b_proj ----------------
__global__ void prep_kernel(const float* __restrict__ w_ih, const float* __restrict__ w_proj,
                            const float* __restrict__ b_proj, const float* __restrict__ b_ih,
                            float* __restrict__ Wc, float* __restrict__ bc) {
  int idx = blockIdx.x * 256 + threadIdx.x;
  if (idx < G3N * INN) {
    int j = idx / INN, i = idx % INN;
    float a = 0.0f;
    for (int k = 0; k < SDN; k++) a += w_ih[j * SDN + k] * w_proj[k * INN + i];
    Wc[idx] = a;
  }
  if (idx < G3N) {
    float a = b_ih[idx];
    for (int k = 0; k < SDN; k++) a += w_ih[idx * SDN + k] * b_proj[k];
    bc[idx] = a;
  }
}

// ---------------- gx GEMM (transposed out): gxT[c][row] = X[row][:] . Wc[c][:] + bc[c] ----------------
__global__ __launch_bounds__(256)
void gx_gemm(const float* __restrict__ x, const float* __restrict__ Wc,
             const float* __restrict__ bc, float* __restrict__ gxT) {
  __shared__ __align__(16) float WcS[G3N * INN];   // 32 KB
  __shared__ float bcS[G3N];
  const int tid = threadIdx.x;
  const float4* wc4 = (const float4*)Wc;
  float4* wcs4 = (float4*)WcS;
  for (int i = tid; i < G3N * INN / 4; i += 256) wcs4[i] = wc4[i];
  if (tid < G3N) bcS[tid] = bc[tid];
  __syncthreads();

  const size_t row = (size_t)blockIdx.x * 256 + tid;   // exactly BT rows
  v2f xr[INN / 2];
#pragma unroll
  for (int i = 0; i < INN / 4; i++) {
    float4 v = *reinterpret_cast<const float4*>(&x[row * INN + i * 4]);
    xr[2 * i]     = (v2f){v.x, v.y};
    xr[2 * i + 1] = (v2f){v.z, v.w};
  }
  for (int c = 0; c < G3N; c++) {
    const v2f* w = (const v2f*)&WcS[c * INN];
    v2f acc2 = (v2f){bcS[c], 0.0f};
#pragma unroll
    for (int i = 0; i < INN / 2; i++) acc2 = __builtin_elementwise_fma(w[i], xr[i], acc2);
    gxT[(size_t)c * BT + row] = acc2.x + acc2.y;
  }
}

// ---------------- recurrence: one wave per batch element ----------------
__global__ __launch_bounds__(64, 1)
void rec_kernel(const float* __restrict__ gxT,      // [126][BT]
                const float* __restrict__ w_hh,     // [126][42]
                const float* __restrict__ b_hh,     // [126]
                const float* __restrict__ w_bridge, // [128][42]
                const float* __restrict__ b_bridge, // [128]
                const float* __restrict__ w_jump,   // [128]
                const float* __restrict__ b_jump,   // [1]
                const float* __restrict__ w_gate,   // [128]
                const float* __restrict__ b_gate,   // [1]
                const float* __restrict__ theta,    // [1]
                float* __restrict__ hbuf,           // [B][T][HS]
                float* __restrict__ ptrbuf) {       // [B][T]
  const int b = blockIdx.x;
  const int lane = threadIdx.x;
  const int jj = (lane < SDN) ? lane : (SDN - 1);  // clamped gate row
  const int r1 = lane + 64;

  __shared__ float2 JG[RINGN];
  __shared__ __align__(16) float h_buf[HS];

  for (int i = lane; i < RINGN; i += 64) JG[i] = make_float2(0.f, 0.f);
  if (lane < HS) h_buf[lane] = 0.0f;

  // register-resident weight rows
  const v2f* whh2 = (const v2f*)w_hh;
  const v2f* wb2  = (const v2f*)w_bridge;
  v2f Whr[21], Whz[21], Whn[21], Wb0[21], Wb1[21];
#pragma unroll
  for (int k = 0; k < 21; k++) {
    Whr[k] = whh2[jj * 21 + k];
    Whz[k] = whh2[(jj + SDN) * 21 + k];
    Whn[k] = whh2[(jj + 2 * SDN) * 21 + k];
    Wb0[k] = wb2[lane * 21 + k];
    Wb1[k] = wb2[r1 * 21 + k];
  }
  const float bhr = b_hh[jj], bhz = b_hh[jj + SDN], bhn = b_hh[jj + 2 * SDN];
  const float bb0 = b_bridge[lane], bb1 = b_bridge[r1];
  const float wj0 = w_jump[lane], wj1 = w_jump[r1];
  const float wg0 = w_gate[lane], wg1 = w_gate[r1];
  const float bj = b_jump[0], bg = b_gate[0];

  v2f hv2[22];
#pragma unroll
  for (int k = 0; k < 22; k++) hv2[k] = (v2f){0.f, 0.f};
  float hprev = 0.0f;

  float ptr = wrap256(theta[0]);

  const float* gp0 = gxT + (size_t)jj * BT + (size_t)b * TN;
  const float* gp1 = gp0 + (size_t)SDN * BT;
  const float* gp2 = gp1 + (size_t)SDN * BT;
  float* hb = hbuf + (size_t)b * TN * HS;
  float* pb = ptrbuf + (size_t)b * TN;

  float pgx0 = gp0[0], pgx1 = gp1[0], pgx2 = gp2[0];

  // prologue: taps at initial ptr (normalized) + pre-read of J/G window
  float wk[5]; float2 Vk[5];
  {
    int posk[5];
    taps_norm(ptr, posk, wk);
#pragma unroll
    for (int k = 0; k < 5; k++) Vk[k] = JG[posk[k]];
  }
  float pjprev = 0.f, pgprev = 0.f, S2prev = 0.f;

  for (int t = 0; t < TN; t++) {
    // ---- A: pointer chain ----
    float dotJ = 0.f, dotG = 0.f;
#pragma unroll
    for (int k = 0; k < 5; k++) { dotJ += wk[k] * Vk[k].x; dotG += wk[k] * Vk[k].y; }
    float Jv = fmaf(pjprev, S2prev, dotJ);
    float Gv = fmaf(pgprev, S2prev, dotG);
    float jump = 256.0f * sigm(Jv + bj);
    float gate = sigm(Gv + bg);
    float delta = wrap256(jump - ptr + 128.0f) - 128.0f;
    float ptr2 = wrap256(ptr + gate * delta);

    // taps(ptr2): unnormalized + inv
    float tbase = floorf(ptr2);
    float frac = ptr2 - tbase;
    int ib = (int)tbase;
    float e2[5], s = 0.f; int pos2[5];
#pragma unroll
    for (int k = 0; k < 5; k++) {
      float d = (float)(k - 2) - frac;
      e2[k] = __expf(-(d * d) * 0.125f);
      s += e2[k];
      pos2[k] = (ib + k - 2) & 255;
    }
    float inv2 = 1.0f / s;
    // pre-read J/G for next iteration (before this iter's ds_adds)
    float2 Vk2[5];
#pragma unroll
    for (int k = 0; k < 5; k++) Vk2[k] = JG[pos2[k]];
    float w2n[5], S2 = 0.f;
#pragma unroll
    for (int k = 0; k < 5; k++) { w2n[k] = e2[k] * inv2; S2 = fmaf(w2n[k], w2n[k], S2); }
    if (lane == 0) pb[t] = ptr2;

    // ---- B: h chain ----
    v2f ar = (v2f){bhr, 0.f}, az = (v2f){bhz, 0.f}, an = (v2f){bhn, 0.f};
#pragma unroll
    for (int k = 0; k < 21; k++) {
      v2f h2 = hv2[k];
      ar = __builtin_elementwise_fma(Whr[k], h2, ar);
      az = __builtin_elementwise_fma(Whz[k], h2, az);
      an = __builtin_elementwise_fma(Whn[k], h2, an);
    }
    float ghr = ar.x + ar.y, ghz = az.x + az.y, ghn = an.x + an.y;
    float rg = sigm(pgx0 + ghr);
    float zg = sigm(pgx1 + ghz);
    float ng = tanhfast(pgx2 + rg * ghn);
    float hn = (1.0f - zg) * ng + zg * hprev;
    hprev = hn;
    if (lane < SDN) {
      h_buf[lane] = hn;
      hb[(size_t)t * HS + lane] = hn;
    }
    // broadcast h' (uniform LDS reads)
#pragma unroll
    for (int i = 0; i < 11; i++) {
      float4 v = *reinterpret_cast<const float4*>(&h_buf[i * 4]);
      hv2[2 * i]     = (v2f){v.x, v.y};
      hv2[2 * i + 1] = (v2f){v.z, v.w};
    }
    // prefetch gx(t+1)
    if (t + 1 < TN) { pgx0 = gp0[t + 1]; pgx1 = gp1[t + 1]; pgx2 = gp2[t + 1]; }

    // u = tanh(Wb h' + bb), dims lane, lane+64
    v2f a0 = (v2f){bb0, 0.f}, a1 = (v2f){bb1, 0.f};
#pragma unroll
    for (int k = 0; k < 21; k++) {
      v2f h2 = hv2[k];
      a0 = __builtin_elementwise_fma(Wb0[k], h2, a0);
      a1 = __builtin_elementwise_fma(Wb1[k], h2, a1);
    }
    float u0 = tanhfast(a0.x + a0.y);
    float u1 = tanhfast(a1.x + a1.y);

    float pjs = wave_sum64(u0 * wj0 + u1 * wj1);
    float pgs = wave_sum64(u0 * wg0 + u1 * wg1);

    // ---- C: J/G scatter-add (lanes 0..4) ----
    int p2sel = pos2[0]; float w2sel = w2n[0];
#pragma unroll
    for (int k = 1; k < 5; k++) {
      if (lane == k) { p2sel = pos2[k]; w2sel = w2n[k]; }
    }
    if (lane < 5) {
      atomicAdd(&JG[p2sel].x, w2sel * pjs);
      atomicAdd(&JG[p2sel].y, w2sel * pgs);
    }

    // rotate loop state
#pragma unroll
    for (int k = 0; k < 5; k++) { wk[k] = w2n[k]; Vk[k] = Vk2[k]; }
    S2prev = S2; pjprev = pjs; pgprev = pgs; ptr = ptr2;
  }
}

// ---------------- r reconstruction: r[b] = sum_t c(t) * tanh(Wb h(t) + bb) ----------------
__global__ __launch_bounds__(64)
void rfinal_kernel(const float* __restrict__ hbuf, const float* __restrict__ ptrbuf,
                   const float* __restrict__ w_bridge, const float* __restrict__ b_bridge,
                   float* __restrict__ rbuf) {
  const int b = blockIdx.x;
  const int chunk = blockIdx.y;     // 4 chunks of 128 steps
  const int lane = threadIdx.x;
  const int t0 = chunk * 128;
  const int r1 = lane + 64;

  __shared__ float c_lds[128];

  const float* pb = ptrbuf + (size_t)b * TN;
  float ptrf = pb[TN - 1];
  int posf[5]; float wf[5];
  taps_norm(ptrf, posf, wf);

#pragma unroll
  for (int rr = 0; rr < 2; rr++) {
    int tt = rr * 64 + lane;
    int p2[5]; float w2[5];
    taps_norm(pb[t0 + tt], p2, w2);
    float c = 0.0f;
#pragma unroll
    for (int k = 0; k < 5; k++)
#pragma unroll
      for (int k2 = 0; k2 < 5; k2++)
        c += (posf[k] == p2[k2]) ? wf[k] * w2[k2] : 0.0f;
    c_lds[tt] = c;
  }
  __builtin_amdgcn_wave_barrier();

  const v2f* wb2 = (const v2f*)w_bridge;
  v2f Wb0[21], Wb1[21];
#pragma unroll
  for (int k = 0; k < 21; k++) { Wb0[k] = wb2[lane * 21 + k]; Wb1[k] = wb2[r1 * 21 + k]; }
  float bb0 = b_bridge[lane], bb1 = b_bridge[r1];

  float racc0 = 0.0f, racc1 = 0.0f;
  for (int tt = 0; tt < 128; tt++) {
    float ct = c_lds[tt];              // uniform across wave
    if (ct != 0.0f) {
      const float4* hp = (const float4*)(hbuf + ((size_t)b * TN + t0 + tt) * HS);
      v2f hx[22];
#pragma unroll
      for (int i = 0; i < 11; i++) {
        float4 v = hp[i];
        hx[2 * i]     = (v2f){v.x, v.y};
        hx[2 * i + 1] = (v2f){v.z, v.w};
      }
      v2f a0 = (v2f){bb0, 0.f}, a1 = (v2f){bb1, 0.f};
#pragma unroll
      for (int k = 0; k < 21; k++) {
        a0 = __builtin_elementwise_fma(Wb0[k], hx[k], a0);
        a1 = __builtin_elementwise_fma(Wb1[k], hx[k], a1);
      }
      racc0 += ct * tanhfast(a0.x + a0.y);
      racc1 += ct * tanhfast(a1.x + a1.y);
    }
  }
  atomicAdd(&rbuf[b * DD + lane], racc0);
  atomicAdd(&rbuf[b * DD + 64 + lane], racc1);
}

// ---------------- classifier: out = r @ w_cls.T + b_cls ----------------
__global__ __launch_bounds__(256)
void cls_kernel(const float* __restrict__ rbuf, const float* __restrict__ w_cls,
                const float* __restrict__ b_cls, float* __restrict__ out) {
  const int b = blockIdx.x;
  const int tid = threadIdx.x;
  __shared__ __align__(16) float r[DD];
  if (tid < DD) r[tid] = rbuf[b * DD + tid];
  __syncthreads();

  for (int c = tid; c < NCN; c += 256) {
    float acc = b_cls[c];
    const float* wrow = &w_cls[(size_t)c * DD];
#pragma unroll
    for (int d4 = 0; d4 < DD / 4; d4++) {
      float4 wv = *reinterpret_cast<const float4*>(&wrow[d4 * 4]);
      float4 rv = *reinterpret_cast<const float4*>(&r[d4 * 4]);
      acc += wv.x * rv.x + wv.y * rv.y + wv.z * rv.z + wv.w * rv.w;
    }
    out[(size_t)b * NCN + c] = acc;
  }
}

extern "C" void kernel_launch(void* const* d_in, const int* in_sizes, int n_in,
                              void* d_out, int out_size, void* d_ws, size_t ws_size,
                              hipStream_t stream) {
  const float* x        = (const float*)d_in[0];
  const float* theta    = (const float*)d_in[1];
  const float* w_proj   = (const float*)d_in[2];
  const float* b_proj   = (const float*)d_in[3];
  const float* w_ih     = (const float*)d_in[4];
  const float* w_hh     = (const float*)d_in[5];
  const float* b_ih     = (const float*)d_in[6];
  const float* b_hh     = (const float*)d_in[7];
  const float* w_bridge = (const float*)d_in[8];
  const float* b_bridge = (const float*)d_in[9];
  const float* w_jump   = (const float*)d_in[10];
  const float* b_jump   = (const float*)d_in[11];
  const float* w_gate   = (const float*)d_in[12];
  const float* b_gate   = (const float*)d_in[13];
  const float* w_cls    = (const float*)d_in[14];
  const float* b_cls    = (const float*)d_in[15];
  float* out = (float*)d_out;

  char* ws = (char*)d_ws;
  size_t off = 0;
  float* gxT    = (float*)(ws + off); off += (size_t)G3N * BT * 4;       // 132 MB
  float* hbuf   = (float*)(ws + off); off += (size_t)BN * TN * HS * 4;   // 46 MB
  float* ptrbuf = (float*)(ws + off); off += (size_t)BN * TN * 4;        // 1 MB
  float* rbuf   = (float*)(ws + off); off += (size_t)BN * DD * 4;        // 256 KB
  float* Wc     = (float*)(ws + off); off += (((size_t)G3N * INN * 4 + 255) & ~(size_t)255);
  float* bc     = (float*)(ws + off); off += 512;

  hipMemsetAsync(rbuf, 0, (size_t)BN * DD * 4, stream);
  prep_kernel<<<32, 256, 0, stream>>>(w_ih, w_proj, b_proj, b_ih, Wc, bc);
  gx_gemm<<<BT / 256, 256, 0, stream>>>(x, Wc, bc, gxT);
  rec_kernel<<<BN, 64, 0, stream>>>(gxT, w_hh, b_hh, w_bridge, b_bridge,
                                    w_jump, b_jump, w_gate, b_gate, theta, hbuf, ptrbuf);
  dim3 gfin(BN, 4);
  rfinal_kernel<<<gfin, 64, 0, stream>>>(hbuf, ptrbuf, w_bridge, b_bridge, rbuf);
  cls_kernel<<<BN, 256, 0, stream>>>(rbuf, w_cls, b_cls, out);
}